// Round 3
// baseline (107.992 us; speedup 1.0000x reference)
//
#include <hip/hip_runtime.h>

// Problem constants (fixed by the reference setup_inputs): B=2048, C=2704, D=5
#define N_CELLS (2048 * 2704)          // 5,537,792 cells, divisible by 4
#define N_QUADS (N_CELLS / 4)          // 1,384,448
#define RBLOCKS 2048
#define RTHREADS 256
#define GSTRIDE (RBLOCKS * RTHREADS)
#define LOG_CLAMP (-100.0f)

// Fused single-pass loss:
//  - grid-stride over quads of 4 cells (20 floats = 5 aligned float4 per array,
//    10 independent loads per iteration -> good MLP; R0 pattern, which benched
//    faster than the fully-coalesced R1 variant at identical HW kernel time)
//  - per-block partials {face_cnt, sum_box, sum_bce, sum_bg} -> ws[bid*4..]
//  - last-block-done ticket (store ws -> __threadfence -> atomicAdd; winner
//    fences and reduces all 2048 partials deterministically) saves the second
//    launch + inter-kernel drain of the 2-pass version.
__global__ __launch_bounds__(RTHREADS) void mloss_fused(
    const float* __restrict__ x, const float* __restrict__ y,
    float* __restrict__ ws, unsigned* __restrict__ counter,
    float* __restrict__ out) {
  float cnt = 0.f, sbox = 0.f, sbce = 0.f, sbg = 0.f;

  const int tid = blockIdx.x * RTHREADS + threadIdx.x;

  for (int q = tid; q < N_QUADS; q += GSTRIDE) {
    const float4* xp = reinterpret_cast<const float4*>(x + (size_t)q * 20);
    const float4* yp = reinterpret_cast<const float4*>(y + (size_t)q * 20);
    float xa[20], ya[20];
#pragma unroll
    for (int k = 0; k < 5; ++k) {
      float4 v = xp[k];
      xa[4 * k + 0] = v.x; xa[4 * k + 1] = v.y;
      xa[4 * k + 2] = v.z; xa[4 * k + 3] = v.w;
    }
#pragma unroll
    for (int k = 0; k < 5; ++k) {
      float4 v = yp[k];
      ya[4 * k + 0] = v.x; ya[4 * k + 1] = v.y;
      ya[4 * k + 2] = v.z; ya[4 * k + 3] = v.w;
    }
#pragma unroll
    for (int c2 = 0; c2 < 4; ++c2) {
      const int b = 5 * c2;
      float t = ya[b];
      float c = xa[b];
      float lc  = fmaxf(__logf(c), LOG_CLAMP);
      float l1c = fmaxf(__logf(1.f - c), LOG_CLAMP);
      float d1 = xa[b + 1] - ya[b + 1];
      float d2 = xa[b + 2] - ya[b + 2];
      float d3 = xa[b + 3] - ya[b + 3];
      float d4 = xa[b + 4] - ya[b + 4];
      float se = d1 * d1 + d2 * d2 + d3 * d3 + d4 * d4;
      float bce = -(t * lc + (1.f - t) * l1c);
      bool m = (t > 0.5f);
      cnt  += m ? 1.f : 0.f;
      sbox += m ? se : 0.f;
      sbce += m ? bce : 0.f;
      sbg  += m ? 0.f : -l1c;
    }
  }

  // wave (64-lane) reduce
#pragma unroll
  for (int off = 32; off; off >>= 1) {
    cnt  += __shfl_down(cnt, off);
    sbox += __shfl_down(sbox, off);
    sbce += __shfl_down(sbce, off);
    sbg  += __shfl_down(sbg, off);
  }

  __shared__ float red[4][4];
  __shared__ int is_last;
  const int wave = threadIdx.x >> 6;
  if ((threadIdx.x & 63) == 0) {
    red[wave][0] = cnt; red[wave][1] = sbox;
    red[wave][2] = sbce; red[wave][3] = sbg;
  }
  __syncthreads();
  if (threadIdx.x == 0) {
    float r0 = 0.f, r1 = 0.f, r2 = 0.f, r3 = 0.f;
#pragma unroll
    for (int w = 0; w < 4; ++w) {
      r0 += red[w][0]; r1 += red[w][1]; r2 += red[w][2]; r3 += red[w][3];
    }
    float* o = ws + (size_t)blockIdx.x * 4;
    o[0] = r0; o[1] = r1; o[2] = r2; o[3] = r3;
    __threadfence();                         // release: ws visible device-wide
    unsigned ticket = atomicAdd(counter, 1u);
    is_last = (ticket == RBLOCKS - 1) ? 1 : 0;
  }
  __syncthreads();
  if (!is_last) return;

  // last block: acquire, then deterministic reduce of all block partials
  __threadfence();
  float r0 = 0.f, r1 = 0.f, r2 = 0.f, r3 = 0.f;
  for (int i = threadIdx.x; i < RBLOCKS; i += RTHREADS) {
    const float* p = ws + (size_t)i * 4;
    r0 += p[0]; r1 += p[1]; r2 += p[2]; r3 += p[3];
  }
#pragma unroll
  for (int off = 32; off; off >>= 1) {
    r0 += __shfl_down(r0, off);
    r1 += __shfl_down(r1, off);
    r2 += __shfl_down(r2, off);
    r3 += __shfl_down(r3, off);
  }
  __syncthreads();
  if ((threadIdx.x & 63) == 0) {
    red[wave][0] = r0; red[wave][1] = r1;
    red[wave][2] = r2; red[wave][3] = r3;
  }
  __syncthreads();
  if (threadIdx.x == 0) {
    float fcnt = 0.f, fbox = 0.f, fbce = 0.f, fbg = 0.f;
#pragma unroll
    for (int w = 0; w < 4; ++w) {
      fcnt += red[w][0]; fbox += red[w][1]; fbce += red[w][2]; fbg += red[w][3];
    }
    float face_num = fcnt;
    float bg_num = (float)N_CELLS - fcnt;
    float scale = 1.f + 1.f / face_num;
    out[0] = scale * (fbox / (4.f * face_num) + fbce / face_num) + fbg / bg_num;
  }
}

extern "C" void kernel_launch(void* const* d_in, const int* in_sizes, int n_in,
                              void* d_out, int out_size, void* d_ws, size_t ws_size,
                              hipStream_t stream) {
  const float* x = (const float*)d_in[0];
  const float* y = (const float*)d_in[1];
  float* ws = (float*)d_ws;                       // 2048*4 floats = 32 KiB
  unsigned* counter = (unsigned*)((char*)d_ws + RBLOCKS * 4 * sizeof(float));
  float* out = (float*)d_out;

  hipMemsetAsync(counter, 0, sizeof(unsigned), stream);  // ticket reset per call
  mloss_fused<<<RBLOCKS, RTHREADS, 0, stream>>>(x, y, ws, counter, out);
}

// Round 4
// 38.053 us; speedup vs baseline: 2.8379x; 2.8379x over previous
//
#include <hip/hip_runtime.h>

// Problem constants (fixed by the reference setup_inputs): B=2048, C=2704, D=5
#define N_CELLS (2048 * 2704)          // 5,537,792 cells, divisible by 4
#define N_QUADS (N_CELLS / 4)          // 1,384,448
#define P1_BLOCKS 1024
#define P1_THREADS 512                 // 1024x512 = 524,288 threads, 32 waves/CU
#define GSTRIDE (P1_BLOCKS * P1_THREADS)
#define P2_THREADS 256
#define LOG_CLAMP (-100.0f)

// Pass 1: grid-stride over quads of 4 cells (20 floats = 5 aligned float4 per
// array). R0's proven access pattern: 10 independent dwordx4 loads per iter.
// Per-block partials {face_cnt, sum_box, sum_bce, sum_bg} stored as one float4.
// NOTE (R2 lesson): do NOT fuse the final reduce via threadfence/ticket —
// device-scope fences collapsed memory throughput 2x on gfx950.
__global__ __launch_bounds__(P1_THREADS) void mloss_partial(
    const float* __restrict__ x, const float* __restrict__ y,
    float4* __restrict__ ws) {
  float cnt = 0.f, sbox = 0.f, sbce = 0.f, sbg = 0.f;

  const int tid = blockIdx.x * P1_THREADS + threadIdx.x;

  for (int q = tid; q < N_QUADS; q += GSTRIDE) {
    const float4* xp = reinterpret_cast<const float4*>(x + (size_t)q * 20);
    const float4* yp = reinterpret_cast<const float4*>(y + (size_t)q * 20);
    float xa[20], ya[20];
#pragma unroll
    for (int k = 0; k < 5; ++k) {
      float4 v = xp[k];
      xa[4 * k + 0] = v.x; xa[4 * k + 1] = v.y;
      xa[4 * k + 2] = v.z; xa[4 * k + 3] = v.w;
    }
#pragma unroll
    for (int k = 0; k < 5; ++k) {
      float4 v = yp[k];
      ya[4 * k + 0] = v.x; ya[4 * k + 1] = v.y;
      ya[4 * k + 2] = v.z; ya[4 * k + 3] = v.w;
    }
#pragma unroll
    for (int c2 = 0; c2 < 4; ++c2) {
      const int b = 5 * c2;
      float t = ya[b];
      float c = xa[b];
      // log terms, clamped like torch BCE; 1-c exact for c in [0.5,1).
      float lc  = fmaxf(__logf(c), LOG_CLAMP);
      float l1c = fmaxf(__logf(1.f - c), LOG_CLAMP);
      float d1 = xa[b + 1] - ya[b + 1];
      float d2 = xa[b + 2] - ya[b + 2];
      float d3 = xa[b + 3] - ya[b + 3];
      float d4 = xa[b + 4] - ya[b + 4];
      float se = d1 * d1 + d2 * d2 + d3 * d3 + d4 * d4;
      float bce = -(t * lc + (1.f - t) * l1c);
      bool m = (t > 0.5f);
      cnt  += m ? 1.f : 0.f;
      sbox += m ? se : 0.f;
      sbce += m ? bce : 0.f;
      sbg  += m ? 0.f : -l1c;
    }
  }

  // wave (64-lane) reduce
#pragma unroll
  for (int off = 32; off; off >>= 1) {
    cnt  += __shfl_down(cnt, off);
    sbox += __shfl_down(sbox, off);
    sbce += __shfl_down(sbce, off);
    sbg  += __shfl_down(sbg, off);
  }

  __shared__ float4 red[P1_THREADS / 64];  // 8 waves
  const int wave = threadIdx.x >> 6;
  if ((threadIdx.x & 63) == 0)
    red[wave] = make_float4(cnt, sbox, sbce, sbg);
  __syncthreads();
  if (threadIdx.x == 0) {
    float4 s = red[0];
#pragma unroll
    for (int w = 1; w < P1_THREADS / 64; ++w) {
      float4 r = red[w];
      s.x += r.x; s.y += r.y; s.z += r.z; s.w += r.w;
    }
    ws[blockIdx.x] = s;
  }
}

// Pass 2: one block deterministically reduces the 1024 float4 partials
// (4 per thread, vectorized) and applies the final loss formula.
__global__ __launch_bounds__(P2_THREADS) void mloss_final(
    const float4* __restrict__ ws, float* __restrict__ out) {
  float r0 = 0.f, r1 = 0.f, r2 = 0.f, r3 = 0.f;
#pragma unroll
  for (int k = 0; k < P1_BLOCKS / P2_THREADS; ++k) {
    float4 p = ws[k * P2_THREADS + threadIdx.x];
    r0 += p.x; r1 += p.y; r2 += p.z; r3 += p.w;
  }
#pragma unroll
  for (int off = 32; off; off >>= 1) {
    r0 += __shfl_down(r0, off);
    r1 += __shfl_down(r1, off);
    r2 += __shfl_down(r2, off);
    r3 += __shfl_down(r3, off);
  }
  __shared__ float4 red[P2_THREADS / 64];
  const int wave = threadIdx.x >> 6;
  if ((threadIdx.x & 63) == 0)
    red[wave] = make_float4(r0, r1, r2, r3);
  __syncthreads();
  if (threadIdx.x == 0) {
    float cnt = 0.f, sbox = 0.f, sbce = 0.f, sbg = 0.f;
#pragma unroll
    for (int w = 0; w < P2_THREADS / 64; ++w) {
      float4 r = red[w];
      cnt += r.x; sbox += r.y; sbce += r.z; sbg += r.w;
    }
    float face_num = cnt;
    float bg_num = (float)N_CELLS - cnt;
    float scale = 1.f + 1.f / face_num;
    out[0] = scale * (sbox / (4.f * face_num) + sbce / face_num) + sbg / bg_num;
  }
}

extern "C" void kernel_launch(void* const* d_in, const int* in_sizes, int n_in,
                              void* d_out, int out_size, void* d_ws, size_t ws_size,
                              hipStream_t stream) {
  const float* x = (const float*)d_in[0];
  const float* y = (const float*)d_in[1];
  float4* ws = (float4*)d_ws;          // P1_BLOCKS float4 = 16 KiB
  float* out = (float*)d_out;

  mloss_partial<<<P1_BLOCKS, P1_THREADS, 0, stream>>>(x, y, ws);
  mloss_final<<<1, P2_THREADS, 0, stream>>>(ws, out);
}